// Round 15
// baseline (283.701 us; speedup 1.0000x reference)
//
#include <hip/hip_runtime.h>
#include <stdint.h>

typedef unsigned short u16;
typedef unsigned char u8;
typedef unsigned int u32;
typedef __attribute__((ext_vector_type(8))) short short8x;
typedef __attribute__((ext_vector_type(4))) float f32x4;
typedef __attribute__((ext_vector_type(16))) float f32x16;

#define DEV static __device__ __forceinline__

DEV u16 f2bf(float f) {
  union { float f; unsigned u; } v; v.f = f;
  unsigned r = v.u + 0x7FFFu + ((v.u >> 16) & 1u);
  return (u16)(r >> 16);
}
DEV int imin(int a, int b) { return a < b ? a : b; }
DEV int imax(int a, int b) { return a > b ? a : b; }
DEV float ex2(float x) { return __builtin_exp2f(x); }

DEV void gload16(const void* g, void* l) {
  __builtin_amdgcn_global_load_lds((const __attribute__((address_space(1))) void*)g,
                                   (__attribute__((address_space(3))) void*)l, 16, 0, 0);
}

DEV u32 cvtpk_bf16(float lo, float hi) {
  u32 r;
  asm("v_cvt_pk_bf16_f32 %0, %1, %2" : "=v"(r) : "v"(lo), "v"(hi));
  return r;
}
DEV void plswap(u32& a, u32& b) {
  asm("v_permlane32_swap_b32 %0, %1" : "+v"(a), "+v"(b));
}

#define LOG2E 1.44269504f

// ---------------------------------------------------------------------------
// Fused prep: blocks 0..1007 wconv (7 mats x 144 tiles); 1008..2031 embed
// (grid-stride); 2032 bits; 2033..2128 hgather-direct (h[clss] from emb/pos).
struct WPtrs { const float* p[7]; };

__global__ __launch_bounds__(256) void prep_kernel(
    WPtrs wp, const int* __restrict__ x, const float* __restrict__ emb,
    const float* __restrict__ pos, const int* __restrict__ clss,
    const int* __restrict__ mask, u16* __restrict__ wt, u16* __restrict__ hb,
    u16* __restrict__ hg, u32* __restrict__ kv32, u32* __restrict__ mv32,
    u32* __restrict__ mc32) {
  __shared__ __align__(16) char smraw[64 * 72 * 4];
  const int bid = blockIdx.x;
  const int t = threadIdx.x;

  if (bid < 1008) {
    // ---- weight convert+transpose: w[k][n] fp32 -> wt[mat][n][k] bf16 ----
    const int mat = bid / 144;
    const int inner = bid - mat * 144;
    const int kt = inner % 12, nt = inner / 12;
    const float* __restrict__ w = wp.p[mat];
    float(*tile)[72] = (float(*)[72])smraw;
    {
      const int kk = t >> 2, n0 = (t & 3) * 16;
      const float* src = w + (size_t)(kt * 64 + kk) * 768 + nt * 64 + n0;
#pragma unroll
      for (int i = 0; i < 4; ++i)
        *(float4*)&tile[kk][n0 + i * 4] = *(const float4*)(src + i * 4);
    }
    __syncthreads();
    {
      const int nn = t >> 2, k0 = (t & 3) * 16;
      u16* dst = wt + (size_t)(mat * 768 + nt * 64 + nn) * 768 + kt * 64 + k0;
      short8x v0, v1;
#pragma unroll
      for (int j = 0; j < 8; ++j) {
        v0[j] = (short)f2bf(tile[k0 + j][nn]);
        v1[j] = (short)f2bf(tile[k0 + 8 + j][nn]);
      }
      *(short8x*)dst = v0;
      *(short8x*)(dst + 8) = v1;
    }
    return;
  }
  if (bid < 2032) {
    // ---- h = emb[x] + pos -> bf16 (8192 x 768) ----
    const int vb = bid - 1008;
    const int n4 = 2 * 4096 * 192;
    for (int i = vb * 256 + t; i < n4; i += 1024 * 256) {
      const int r = i / 192;
      const int d4 = i - r * 192;
      const int s = r & 4095;
      const int tok = x[r];
      const float4 e = *(const float4*)(emb + (size_t)tok * 768 + d4 * 4);
      const float4 p = *(const float4*)(pos + (size_t)s * 768 + d4 * 4);
      union { u16 u[4]; uint2 v; } o;
      o.u[0] = f2bf(e.x + p.x);
      o.u[1] = f2bf(e.y + p.y);
      o.u[2] = f2bf(e.z + p.z);
      o.u[3] = f2bf(e.w + p.w);
      *(uint2*)(hb + (size_t)r * 768 + d4 * 4) = o.v;
    }
    return;
  }
  if (bid == 2032) {
    // ---- validity bitmasks ----
    u8* isg = (u8*)smraw;
    for (int i = t; i < 4096; i += 256) isg[i] = 0;
    __syncthreads();
    if (t < 64) isg[clss[t]] = 1;
    __syncthreads();
    {
      const int b = t >> 7, i = t & 127;
      u32 kv = 0, mvv = 0;
      for (int j = 0; j < 32; ++j) {
        const int key = i * 32 + j;
        const u32 m = (u32)(mask[b * 4096 + key] != 0);
        mvv |= m << j;
        kv |= (m & (u32)(isg[key] == 0)) << j;
      }
      kv32[b * 128 + i] = kv;
      mv32[b * 128 + i] = mvv;
    }
    if (t < 4) {
      const int b = t >> 1, wi = t & 1;
      u32 mc = 0;
      for (int j = 0; j < 32; ++j) {
        const int g = wi * 32 + j;
        mc |= (u32)(mask[b * 4096 + clss[g]] != 0) << j;
      }
      mc32[b * 2 + wi] = mc;
    }
    return;
  }
  // ---- hg[128][768]: h at clss rows, computed directly (identical f2bf) ----
  {
    const int i = (bid - 2033) * 256 + t;   // 0..24575 = 128 x 192
    const int r = i / 192, d4 = i - r * 192;
    const int b = r >> 6, g = r & 63;
    const int s = clss[g];
    const int tok = x[b * 4096 + s];
    const float4 e = *(const float4*)(emb + (size_t)tok * 768 + d4 * 4);
    const float4 p = *(const float4*)(pos + (size_t)s * 768 + d4 * 4);
    union { u16 u[4]; uint2 v; } o;
    o.u[0] = f2bf(e.x + p.x);
    o.u[1] = f2bf(e.y + p.y);
    o.u[2] = f2bf(e.z + p.z);
    o.u[3] = f2bf(e.w + p.w);
    *(uint2*)(hg + (size_t)r * 768 + d4 * 4) = o.v;
  }
}

// ---------------------------------------------------------------------------
// 128x128 bf16 MFMA GEMM, B pre-transposed (N x K), BK=64 double-buffered
// global_load_lds pipeline with counted vmcnt (never drains to 0 in-loop),
// raw s_barrier (no implicit vmcnt(0) drain), 4-way-reduced LDS swizzle.
// K = 768 = 12 tiles of 64. XCD-local bx-major mapping (8-by groups).
struct Outs6 { u16* p[6]; };

template <int MODE>
__global__ __launch_bounds__(256) void gemm_kernel(const u16* __restrict__ A, const u16* __restrict__ Bt,
                                                   const u16* __restrict__ A2, const u16* __restrict__ Bt2,
                                                   Outs6 outs, float* __restrict__ outF) {
  __shared__ __align__(16) u16 smA[2][128 * 64];   // 32 KB
  __shared__ __align__(16) u16 smB[2][128 * 64];   // 32 KB
  const int t = threadIdx.x;
  const int l = t & 63, w = t >> 6;
  const int l15 = l & 15, grp = l >> 4;
  const int wm = w >> 1, wn = w & 1;
  int bx, by;
  bool qg = false;
  if (MODE == 0) {
    int id = blockIdx.x;
    if (id >= 1920) {                    // folded qg-compact part
      qg = true;
      bx = id - 1920;
      by = 0;
    } else {                             // 1920 = 8 XCDs x 240; bx-major, 8-by groups
      const int xcd = id & 7;
      const int j = id >> 3;             // 0..239
      by = xcd * 8 + (j & 7);
      bx = j >> 3;                       // 0..29
    }
  } else {                               // 384 = 8 XCDs x 48; bx-major, 8-by groups
    const int xcd = blockIdx.x & 7;
    const int j = blockIdx.x >> 3;       // 0..47
    by = xcd * 8 + (j & 7);
    bx = j >> 3;                         // 0..5
  }
  const u16* __restrict__ Ap = (MODE == 0 && qg) ? A2 : A;
  const u16* __restrict__ Btp = (MODE == 0 && qg) ? Bt2 : Bt;
  const int m0 = by * 128, n0 = bx * 128;
  const f32x4 zero4 = {0.f, 0.f, 0.f, 0.f};
  f32x4 acc[4][4];
#pragma unroll
  for (int mi = 0; mi < 4; ++mi)
#pragma unroll
    for (int ni = 0; ni < 4; ++ni) acc[mi][ni] = zero4;

  const int sr = l >> 3;               // 0..7
  const int scb = (l & 7) * 16;        // dest byte col within row

  auto STAGE = [&](int kb, int d) {
#pragma unroll
    for (int c = 0; c < 4; ++c) {
      const int rg = w * 4 + c;        // 0..15
      const int r = rg * 8 + sr;       // 0..127
      const int sc = scb ^ (((r >> 2) & 3) << 5);
      gload16(Ap + (size_t)(m0 + r) * 768 + kb * 64 + (sc >> 1), (char*)smA[d] + rg * 1024);
      gload16(Btp + (size_t)(n0 + r) * 768 + kb * 64 + (sc >> 1), (char*)smB[d] + rg * 1024);
    }
  };
  const int xorf = ((l15 >> 2) & 3) << 5;
  auto RDA = [&](int d, int mi, int kk) {
    return *(const short8x*)((const char*)smA[d] + (wm * 64 + mi * 16 + l15) * 128 + ((kk * 64 + grp * 16) ^ xorf));
  };
  auto RDB = [&](int d, int ni, int kk) {
    return *(const short8x*)((const char*)smB[d] + (wn * 64 + ni * 16 + l15) * 128 + ((kk * 64 + grp * 16) ^ xorf));
  };

  // prologue: stage tiles 0,1; validate tile 0 (8 of 16 loads retired)
  STAGE(0, 0);
  STAGE(1, 1);
  asm volatile("s_waitcnt vmcnt(8)" ::: "memory");
  __builtin_amdgcn_s_barrier();
  __builtin_amdgcn_sched_barrier(0);

  short8x a0[4], b0[4], a1[4], b1[4];
#pragma unroll
  for (int i = 0; i < 4; ++i) { a0[i] = RDA(0, i, 0); b0[i] = RDB(0, i, 0); }

  for (int kt = 0; kt < 12; ++kt) {
    const int cur = kt & 1;
#pragma unroll
    for (int i = 0; i < 4; ++i) { a1[i] = RDA(cur, i, 1); b1[i] = RDB(cur, i, 1); }
    __builtin_amdgcn_s_setprio(1);
#pragma unroll
    for (int mi = 0; mi < 4; ++mi)
#pragma unroll
      for (int ni = 0; ni < 4; ++ni)
        acc[mi][ni] = __builtin_amdgcn_mfma_f32_16x16x32_bf16(a0[mi], b0[ni], acc[mi][ni], 0, 0, 0);
    __builtin_amdgcn_s_setprio(0);
    if (kt < 11) {
      asm volatile("s_waitcnt lgkmcnt(0)" ::: "memory");
      __builtin_amdgcn_s_barrier();
      __builtin_amdgcn_sched_barrier(0);
      if (kt < 10) {
        STAGE(kt + 2, cur);
        asm volatile("s_waitcnt vmcnt(8)" ::: "memory");
      } else {
        asm volatile("s_waitcnt vmcnt(0)" ::: "memory");
      }
      __builtin_amdgcn_s_barrier();
      __builtin_amdgcn_sched_barrier(0);
#pragma unroll
      for (int i = 0; i < 4; ++i) { a0[i] = RDA(cur ^ 1, i, 0); b0[i] = RDB(cur ^ 1, i, 0); }
    }
    __builtin_amdgcn_s_setprio(1);
#pragma unroll
    for (int mi = 0; mi < 4; ++mi)
#pragma unroll
      for (int ni = 0; ni < 4; ++ni)
        acc[mi][ni] = __builtin_amdgcn_mfma_f32_16x16x32_bf16(a1[mi], b1[ni], acc[mi][ni], 0, 0, 0);
    __builtin_amdgcn_s_setprio(0);
  }

  if (MODE == 0) {
    if (qg) {
      u16* __restrict__ base = outs.p[5];
#pragma unroll
      for (int mi = 0; mi < 4; ++mi)
#pragma unroll
        for (int ni = 0; ni < 4; ++ni) {
          const int col = n0 + wn * 64 + ni * 16 + l15;
          const int hd = col >> 6, dh = col & 63;
#pragma unroll
          for (int rr = 0; rr < 4; ++rr) {
            const int row = wm * 64 + mi * 16 + grp * 4 + rr;   // 0..127
            const int b = row >> 6, g = row & 63;
            base[((size_t)(b * 12 + hd) * 64 + g) * 64 + dh] = f2bf(acc[mi][ni][rr] * 0.125f * LOG2E);
          }
        }
      return;
    }
    const int mat = bx / 6;               // 5 mats: q,k,v,kg,vg
    const int inn0 = n0 - mat * 768 + wn * 64;
    u16* __restrict__ base = outs.p[mat];
    if (mat == 2 || mat == 4) {
#pragma unroll
      for (int mi = 0; mi < 4; ++mi) {
        const int row0 = m0 + wm * 64 + mi * 16 + grp * 4;
        const int b = row0 >> 12, s = row0 & 4095;
#pragma unroll
        for (int ni = 0; ni < 4; ++ni) {
          const int col = inn0 + ni * 16 + l15;
          const int hd = col >> 6, dh = col & 63;
          union { u16 u[4]; uint2 v; } o;
#pragma unroll
          for (int rr = 0; rr < 4; ++rr) o.u[rr] = f2bf(acc[mi][ni][rr]);
          *(uint2*)(base + ((size_t)(b * 12 + hd) * 64 + dh) * 4096 + s) = o.v;
        }
      }
    } else {
      const float scl = (mat == 0) ? 0.125f * LOG2E : 1.0f;
#pragma unroll
      for (int mi = 0; mi < 4; ++mi)
#pragma unroll
        for (int ni = 0; ni < 4; ++ni) {
          const int col = inn0 + ni * 16 + l15;
          const int hd = col >> 6, dh = col & 63;
#pragma unroll
          for (int rr = 0; rr < 4; ++rr) {
            const int row = m0 + wm * 64 + mi * 16 + grp * 4 + rr;
            const int b = row >> 12, s = row & 4095;
            base[((size_t)(b * 12 + hd) * 4096 + s) * 64 + dh] = f2bf(acc[mi][ni][rr] * scl);
          }
        }
    }
  } else {
#pragma unroll
    for (int mi = 0; mi < 4; ++mi)
#pragma unroll
      for (int rr = 0; rr < 4; ++rr) {
        const int row = m0 + wm * 64 + mi * 16 + grp * 4 + rr;
#pragma unroll
        for (int ni = 0; ni < 4; ++ni) {
          const int col = n0 + wn * 64 + ni * 16 + l15;
          outF[(size_t)row * 768 + col] = acc[mi][ni][rr];
        }
      }
  }
}

// ---------------------------------------------------------------------------
// Gather K rows at clss -> kcls; vtcls gathered from vT (v is only stored transposed).
__global__ __launch_bounds__(256) void gcls_kernel(const u16* __restrict__ kB, const u16* __restrict__ vTs,
                                                   const int* __restrict__ clss,
                                                   u16* __restrict__ kcls, u16* __restrict__ vtcls) {
  const int bh = blockIdx.x;
  __shared__ int sc[64];
  const int t = threadIdx.x;
  if (t < 64) sc[t] = clss[t];
  __syncthreads();
  {
    const int g = t >> 2, d0 = (t & 3) * 16;
    const int row = sc[g];
    const u16* pk = kB + ((size_t)bh * 4096 + row) * 64 + d0;
    u16* ok = kcls + ((size_t)bh * 64 + g) * 64 + d0;
    *(short8x*)ok = *(const short8x*)pk;
    *(short8x*)(ok + 8) = *(const short8x*)(pk + 8);
  }
  {
    const int dh = t >> 2, g0 = (t & 3) * 16;
    const u16* vrow = vTs + ((size_t)bh * 64 + dh) * 4096;
    short8x v0, v1;
#pragma unroll
    for (int j = 0; j < 8; ++j) {
      v0[j] = (short)vrow[sc[g0 + j]];
      v1[j] = (short)vrow[sc[g0 + 8 + j]];
    }
    u16* o = vtcls + ((size_t)bh * 64 + dh) * 64 + g0;
    *(short8x*)o = v0;
    *(short8x*)(o + 8) = v1;
  }
}

// ---------------------------------------------------------------------------
// Swapped-operand 32x32 attention core. Softmax fully in-register.
struct AttnState {
  f32x16 a0, a1;   // out^T accumulators for dh-tiles 0,1
  float m, l;
};

// Shared softmax+PV tail given scores s0,s1 and V-fragment loader lambda.
#define ATTN_SOFTMAX_PV(S, s0, s1, vm0, vm1, LOADV0, LOADV1)                        \
  {                                                                                  \
    float mx[8];                                                                     \
    _Pragma("unroll") for (int e = 0; e < 8; ++e)                                    \
        mx[e] = fmaxf(fmaxf(s0[e], s0[e + 8]), fmaxf(s1[e], s1[e + 8]));             \
    mx[0] = fmaxf(mx[0], mx[4]); mx[1] = fmaxf(mx[1], mx[5]);                        \
    mx[2] = fmaxf(mx[2], mx[6]); mx[3] = fmaxf(mx[3], mx[7]);                        \
    mx[0] = fmaxf(mx[0], mx[2]); mx[1] = fmaxf(mx[1], mx[3]);                        \
    float mv = fmaxf(mx[0], mx[1]);                                                  \
    mv = fmaxf(mv, __shfl_xor(mv, 32));                                              \
    if (!__all(mv <= S.m + 8.f)) {                                                   \
      const float mn = fmaxf(S.m, mv);                                               \
      const float sc = ex2(S.m - mn);                                                \
      S.m = mn; S.l *= sc;                                                           \
      _Pragma("unroll") for (int e = 0; e < 16; ++e) { S.a0[e] *= sc; S.a1[e] *= sc; } \
    }                                                                                \
    float p0[16], p1[16];                                                            \
    if ((vm0 & vm1) == 0xFFFFFFFFu) {                                                \
      _Pragma("unroll") for (int e = 0; e < 16; ++e) {                               \
        p0[e] = ex2(s0[e] - S.m); p1[e] = ex2(s1[e] - S.m);                          \
      }                                                                              \
    } else {                                                                         \
      const u32 w0 = vm0 >> (hf * 4), w1 = vm1 >> (hf * 4);                          \
      _Pragma("unroll") for (int e = 0; e < 16; ++e) {                               \
        const int cr = (e & 3) + 8 * (e >> 2);                                       \
        p0[e] = ex2(s0[e] - S.m) * (float)((w0 >> cr) & 1u);                         \
        p1[e] = ex2(s1[e] - S.m) * (float)((w1 >> cr) & 1u);                         \
      }                                                                              \
    }                                                                                \
    float sm[8];                                                                     \
    _Pragma("unroll") for (int e = 0; e < 8; ++e)                                    \
        sm[e] = (p0[e] + p0[e + 8]) + (p1[e] + p1[e + 8]);                           \
    sm[0] += sm[4]; sm[1] += sm[5]; sm[2] += sm[6]; sm[3] += sm[7];                  \
    sm[0] += sm[2]; sm[1] += sm[3];                                                  \
    float ls = sm[0] + sm[1];                                                        \
    ls += __shfl_xor(ls, 32);                                                        \
    S.l += ls;                                                                       \
    _Pragma("unroll") for (int st = 0; st < 2; ++st) {                               \
      const float* pp = st ? p1 : p0;                                                \
      _Pragma("unroll") for (int c = 0; c < 2; ++c) {                                \
        u32 A1 = cvtpk_bf16(pp[8 * c + 0], pp[8 * c + 1]);                           \
        u32 A2 = cvtpk_bf16(pp[8 * c + 2], pp[8 * c + 3]);                           \
        u32 B1 = cvtpk_bf16(pp[8 * c + 4], pp[8 * c + 5]);                           \
        u32 B2 = cvtpk_bf16(pp[8 * c + 6], pp[8 * c + 7]);                           \
        plswap(A1, B1); plswap(A2, B2);                                              \
        union { u32 w[4]; short8x v; } u;                                            \
        u.w[0] = A1; u.w[1] = A2; u.w[2] = B1; u.w[3] = B2;                          \
        const int sc4 = st * 2 + c;                                                  \
        const short8x vf0 = LOADV0(sc4);                                             \
        const short8x vf1 = LOADV1(sc4);                                             \
        S.a0 = __builtin_amdgcn_mfma_f32_32x32x16_bf16(vf0, u.v, S.a0, 0, 0, 0);     \
        S.a1 = __builtin_amdgcn_mfma_f32_32x32x16_bf16(vf1, u.v, S.a1, 0, 0, 0);     \
      }                                                                              \
    }                                                                                \
  }

// Global-memory tile (og path).
DEV void attn_tile64(const u16* __restrict__ kp, const u16* __restrict__ vp, int vstr,
                     u32 vm0, u32 vm1, const short8x* qf, AttnState& S, int l31, int hf) {
  const int h8 = hf * 8;
  const f32x16 z16 = {0.f};
  f32x16 s0 = z16, s1 = z16;
  const u16* kr0 = kp + (size_t)l31 * 64 + h8;
  const u16* kr1 = kr0 + 32 * 64;
#pragma unroll
  for (int ks = 0; ks < 4; ++ks) {
    const short8x kf0 = *(const short8x*)(kr0 + ks * 16);
    const short8x kf1 = *(const short8x*)(kr1 + ks * 16);
    s0 = __builtin_amdgcn_mfma_f32_32x32x16_bf16(kf0, qf[ks], s0, 0, 0, 0);
    s1 = __builtin_amdgcn_mfma_f32_32x32x16_bf16(kf1, qf[ks], s1, 0, 0, 0);
  }
#define LV0(sc4) (*(const short8x*)(vp + (sc4) * 16 + h8 + (size_t)l31 * vstr))
#define LV1(sc4) (*(const short8x*)(vp + (sc4) * 16 + h8 + (size_t)(32 + l31) * vstr))
  ATTN_SOFTMAX_PV(S, s0, s1, vm0, vm1, LV0, LV1)
#undef LV0
#undef LV1
}

// LDS tile (band path): Kl/Vl are [64 rows][128B] with byte-XOR swizzle
// ((row&7)<<4) applied to both the staged source and the reads (rule 21).
DEV void attn_tile64_lds(const char* __restrict__ Kl, const char* __restrict__ Vl,
                         u32 vm0, u32 vm1, const short8x* qf, AttnState& S, int l31, int hf) {
  const int swz = (l31 & 7) << 4;
  const f32x16 z16 = {0.f};
  f32x16 s0 = z16, s1 = z16;
#pragma unroll
  for (int ks = 0; ks < 4; ++ks) {
    const int cb = (hf * 16 + ks * 32) ^ swz;
    const short8x kf0 = *(const short8x*)(Kl + l31 * 128 + cb);
    const short8x kf1 = *(const short8x*)(Kl + (32 + l31) * 128 + cb);
    s0 = __builtin_amdgcn_mfma_f32_32x32x16_bf16(kf0, qf[ks], s0, 0, 0, 0);
    s1 = __builtin_amdgcn_mfma_f32_32x32x16_bf16(kf1, qf[ks], s1, 0, 0, 0);
  }
#define LV0(sc4) (*(const short8x*)(Vl + l31 * 128 + (((sc4) * 32 + hf * 16) ^ swz)))
#define LV1(sc4) (*(const short8x*)(Vl + (32 + l31) * 128 + (((sc4) * 32 + hf * 16) ^ swz)))
  ATTN_SOFTMAX_PV(S, s0, s1, vm0, vm1, LV0, LV1)
#undef LV0
#undef LV1
}

DEV u32 bandmask32(int q, int kb2) {
  const int lo = imax(q - 256 - kb2, 0);
  const int hi = imin(q + 256 - kb2, 31);
  if (hi < lo) return 0u;
  return (0xFFFFFFFFu << lo) & (0xFFFFFFFFu >> (31 - hi));
}

// ---------------------------------------------------------------------------
// Fused attention:
//  blocks 0..95   : global-token partials (wave = (bh,qsub,slice of 8)), global reads
//  blocks 96..863 : band; block = 128 queries (4 waves x 32q); K/V^T staged in
//                   LDS with 2-deep counted-vmcnt pipeline.
// NOTE: min-waves stays at 3 (round-6 spill lesson).
struct FusedArgs {
  const u16 *qB, *kB, *vT, *kcls, *vtcls, *qgc, *kgB, *vgT;
  const u32 *kv32, *mv32, *mc32;
  u16* aout;
  float *pm, *pl, *pacc;
};

__global__ __launch_bounds__(256, 3) void band_kernel(FusedArgs a) {
  const int t = threadIdx.x;
  const int w = t >> 6, l = t & 63;
  const int l31 = l & 31, hf = l >> 5, h4 = hf * 4;
  const f32x16 z16 = {0.f};

  __shared__ __align__(16) char Ktile[2][8192];   // 64 keys x 128B (swizzled rows)
  __shared__ __align__(16) char Vtile[2][8192];   // 64 dh x 128B (swizzled rows)

  if (blockIdx.x < 96) {
    // ---- global-token attention partial (global reads) ----
    const int wid = blockIdx.x * 4 + w;     // 384 waves
    const int sl = wid & 7;
    const int qsub = (wid >> 3) & 1;
    const int bh = wid >> 4;
    const int b = bh / 12;
    const int q = qsub * 32 + l31;

    const u16* kgb = a.kgB + (size_t)bh * 4096 * 64;
    const u16* vgb = a.vgT + (size_t)bh * 64 * 4096;
    short8x qf[4];
#pragma unroll
    for (int ks = 0; ks < 4; ++ks)
      qf[ks] = *(const short8x*)(a.qgc + ((size_t)bh * 64 + q) * 64 + ks * 16 + hf * 8);

    AttnState S;
    S.a0 = z16; S.a1 = z16; S.m = -60.f; S.l = 0.f;
    for (int tt = sl * 8; tt < sl * 8 + 8; ++tt) {
      const int kb = tt * 64;
      const u32 vm0 = a.mv32[b * 128 + tt * 2];
      const u32 vm1 = a.mv32[b * 128 + tt * 2 + 1];
      attn_tile64(kgb + (size_t)kb * 64, vgb + kb, 4096, vm0, vm1, qf, S, l31, hf);
    }
    const int pbase = (bh * 8 + sl) * 64;
    float* pr = a.pacc + ((size_t)pbase + q) * 64;
#pragma unroll
    for (int rq = 0; rq < 4; ++rq) {
      f32x4 v0 = {S.a0[rq * 4 + 0], S.a0[rq * 4 + 1], S.a0[rq * 4 + 2], S.a0[rq * 4 + 3]};
      f32x4 v1 = {S.a1[rq * 4 + 0], S.a1[rq * 4 + 1], S.a1[rq * 4 + 2], S.a1[rq * 4 + 3]};
      *(f32x4*)(pr + rq * 8 + h4) = v0;
      *(f32x4*)(pr + 32 + rq * 8 + h4) = v1;
    }
    if (hf == 0) {
      a.pm[pbase + q] = S.m;
      a.pl[pbase + q] = S.l;
    }
    return;
  }

  // ---- band path: 768 blocks of 128 queries; 4 waves x 32q, shared LDS tiles ----
  int bid = blockIdx.x - 96;
  bid = (bid & 7) * 96 + (bid >> 3);   // XCD chunking (768 = 8 * 96, bijective)
  const int qblk = bid & 31;
  const int h = (bid >> 5) % 12;
  const int b = bid / 384;
  const int bh = b * 12 + h;
  const int q0b = qblk * 128;
  const int q0w = q0b + w * 32;
  const int q = q0w + l31;

  const u16* kbh = a.kB + (size_t)bh * 4096 * 64;
  const u16* vbh = a.vT + (size_t)bh * 64 * 4096;
  const u16* kcb = a.kcls + (size_t)bh * 4096;
  const u16* vcb = a.vtcls + (size_t)bh * 4096;

  short8x qf[4];
#pragma unroll
  for (int ks = 0; ks < 4; ++ks)
    qf[ks] = *(const short8x*)(a.qB + ((size_t)bh * 4096 + q) * 64 + ks * 16 + hf * 8);

  AttnState S;
  S.a0 = z16; S.a1 = z16; S.m = -60.f; S.l = 0.f;

  const int tloB = imax(0, q0b - 256) >> 6;
  const int thiB = imin(63, (q0b + 383) >> 6);
  const int nB = thiB - tloB + 1;                   // block band tiles (6..11); tile nB = clss
  const int tlo_w = (imax(0, q0w - 256) >> 6) - tloB;
  const int thi_w = (imin(63, (q0w + 287) >> 6)) - tloB;

  // stage tile j (j<nB band, j==nB clss) into LDS buf; 4 gload16 per wave.
  auto STAGEi = [&](int j, int buf) {
    const u16* ksrc;
    const u16* vsrc;
    int vstr;
    if (j == nB) { ksrc = kcb; vsrc = vcb; vstr = 64; }
    else {
      ksrc = kbh + (size_t)(tloB + j) * 64 * 64;
      vsrc = vbh + (size_t)(tloB + j) * 64;
      vstr = 4096;
    }
#pragma unroll
    for (int c = 0; c < 2; ++c) {
      const int rw = w + 4 * c;                     // row-group 0..7
      const int row = rw * 8 + (l >> 3);
      const int seg = (l & 7) ^ (row & 7);
      gload16(ksrc + (size_t)row * 64 + seg * 8, Ktile[buf] + rw * 1024);
      gload16(vsrc + (size_t)row * vstr + seg * 8, Vtile[buf] + rw * 1024);
    }
  };

  // prologue: 2-deep prefetch; wait tile 0 only (vmcnt(4): tile 1's 4 loads stay in flight)
  STAGEi(0, 0);
  STAGEi(1, 1);
  asm volatile("s_waitcnt vmcnt(4)" ::: "memory");
  __builtin_amdgcn_s_barrier();
  __builtin_amdgcn_sched_barrier(0);

  for (int i = 0; i <= nB; ++i) {
    const int buf = i & 1;
    const bool isG = (i == nB);
    if (isG || (i >= tlo_w && i <= thi_w)) {
      u32 vm0, vm1;
      if (isG) {
        vm0 = a.mc32[b * 2];
        vm1 = a.mc32[b * 2 + 1];
      } else {
        const int tt = tloB + i;
        const int kb = tt * 64;
        vm0 = a.kv32[b * 128 + tt * 2];
        vm1 = a.kv32[b * 128 + tt * 2 + 1];
        const int d0 = kb - q0w, d1 = kb + 32 - q0w;
        if (d0 < -225 || d0 > 225) vm0 &= bandmask32(q, kb);
        if (d1 < -225 || d1 > 225) vm1 &= bandmask32(q, kb + 32);
      }
      attn_tile64_lds(Ktile[buf], Vtile[buf], vm0, vm1, qf, S, l31, hf);
    }
    if (i < nB) {
      // WAR: all waves done reading buf before restaging it
      asm volatile("s_waitcnt lgkmcnt(0)" ::: "memory");
      __builtin_amdgcn_s_barrier();
      __builtin_amdgcn_sched_barrier(0);
      if (i + 2 <= nB) {
        STAGEi(i + 2, buf);
        asm volatile("s_waitcnt vmcnt(4)" ::: "memory");   // tile i+1 landed; i+2 in flight
      } else {
        asm volatile("s_waitcnt vmcnt(0)" ::: "memory");   // final tile landed
      }
      __builtin_amdgcn_s_barrier();
      __builtin_amdgcn_sched_barrier(0);
    }
  }

  // finalize: out = acc/l, store (B,S,D) bf16 (lane q owns row q)
  const float inv = 1.f / S.l;
  u16* ob = a.aout + ((size_t)b * 4096 + q) * 768 + h * 64;
#pragma unroll
  for (int rq = 0; rq < 4; ++rq) {
    union { u16 s[4]; uint2 v; } o0, o1;
#pragma unroll
    for (int j = 0; j < 4; ++j) {
      o0.s[j] = f2bf(S.a0[rq * 4 + j] * inv);
      o1.s[j] = f2bf(S.a1[rq * 4 + j] * inv);
    }
    *(uint2*)(ob + rq * 8 + h4) = o0.v;
    *(uint2*)(ob + 32 + rq * 8 + h4) = o1.v;
  }
}

// ---------------------------------------------------------------------------
// Global-token attention merge: combine 8 key-slice partials into clss rows of aout.
__global__ __launch_bounds__(256) void ogm_kernel(const float* __restrict__ pm, const float* __restrict__ pl,
                                                  const float* __restrict__ pacc, const int* __restrict__ clss,
                                                  u16* __restrict__ aout) {
  const int bh = blockIdx.x;
  const int b = bh / 12, h = bh % 12;
  const int t = threadIdx.x;
  const int r = t >> 2, cs = (t & 3) * 16;
  float mv[8];
  float M = -1e30f;
#pragma unroll
  for (int s = 0; s < 8; ++s) {
    mv[s] = pm[(bh * 8 + s) * 64 + r];
    M = fmaxf(M, mv[s]);
  }
  float L = 0.f, f[8];
#pragma unroll
  for (int s = 0; s < 8; ++s) {
    f[s] = ex2(mv[s] - M);
    L += pl[(bh * 8 + s) * 64 + r] * f[s];
  }
  float o[16];
#pragma unroll
  for (int j = 0; j < 16; ++j) o[j] = 0.f;
#pragma unroll
  for (int s = 0; s < 8; ++s) {
    const float* pr = pacc + (size_t)(bh * 8 + s) * 4096 + r * 64 + cs;
#pragma unroll
    for (int j4 = 0; j4 < 4; ++j4) {
      const float4 a = *(const float4*)(pr + j4 * 4);
      o[j4 * 4 + 0] += a.x * f[s];
      o[j4 * 4 + 1] += a.y * f[s];
      o[j4 * 4 + 2] += a.z * f[s];
      o[j4 * 4 + 3] += a.w * f[s];
    }
  }
  const float inv = 1.f / L;
  short8x v0, v1;
#pragma unroll
  for (int j = 0; j < 8; ++j) {
    v0[j] = (short)f2bf(o[j] * inv);
    v1[j] = (short)f2bf(o[8 + j] * inv);
  }
  u16* op = aout + ((size_t)b * 4096 + clss[r]) * 768 + h * 64 + cs;
  *(short8x*)op = v0;
  *(short8x*)(op + 8) = v1;
}

// ---------------------------------------------------------------------------
extern "C" void kernel_launch(void* const* d_in, const int* in_sizes, int n_in,
                              void* d_out, int out_size, void* d_ws, size_t ws_size,
                              hipStream_t stream) {
  (void)in_sizes; (void)n_in; (void)out_size; (void)ws_size;
  const int* x = (const int*)d_in[0];
  const int* mask = (const int*)d_in[1];
  const int* clss = (const int*)d_in[2];
  const float* emb = (const float*)d_in[3];
  const float* pos = (const float*)d_in[4];
  const float* wq = (const float*)d_in[5];
  const float* wk = (const float*)d_in[6];
  const float* wv = (const float*)d_in[7];
  const float* wo = (const float*)d_in[8];
  const float* wqg = (const float*)d_in[9];
  const float* wkg = (const float*)d_in[10];
  const float* wvg = (const float*)d_in[11];
  float* out = (float*)d_out;

  char* ws = (char*)d_ws;
  size_t off = 0;
  auto alloc = [&](size_t n) { char* p = ws + off; off = (off + n + 255) & ~(size_t)255; return p; };
  const size_t SZ = (size_t)2 * 12 * 4096 * 64 * 2;  // one (B,H,S,DH) bf16 buffer
  u16* hb = (u16*)alloc(SZ);
  u16* wt = (u16*)alloc((size_t)7 * 768 * 768 * 2);
  u16* qb = (u16*)alloc(SZ);
  u16* kb = (u16*)alloc(SZ);
  u16* kgb = (u16*)alloc(SZ);
  u16* vts = (u16*)alloc(SZ);    // v, stored transposed (B,H,DH,S) by gemm<0>
  u16* vgts = (u16*)alloc(SZ);   // vg, stored transposed
  u16* hg = (u16*)alloc((size_t)128 * 768 * 2);
  u16* qgc = (u16*)alloc((size_t)24 * 64 * 64 * 2);
  u16* kcls = (u16*)alloc((size_t)24 * 64 * 64 * 2);
  u16* vtcls = (u16*)alloc((size_t)24 * 64 * 64 * 2);
  u32* kv32 = (u32*)alloc(256 * 4);
  u32* mv32 = (u32*)alloc(256 * 4);
  u32* mc32 = (u32*)alloc(4 * 4);
  u16* aout = (u16*)alloc(SZ);
  float* pm = (float*)alloc((size_t)192 * 64 * 4);
  float* pl = (float*)alloc((size_t)192 * 64 * 4);
  float* pacc = (float*)alloc((size_t)192 * 4096 * 4);

  WPtrs wp;
  wp.p[0] = wq; wp.p[1] = wk; wp.p[2] = wv; wp.p[3] = wkg; wp.p[4] = wvg; wp.p[5] = wqg; wp.p[6] = wo;

  prep_kernel<<<2129, 256, 0, stream>>>(wp, x, emb, pos, clss, mask, wt, hb, hg, kv32, mv32, mc32);

  Outs6 o5;
  o5.p[0] = qb; o5.p[1] = kb; o5.p[2] = vts; o5.p[3] = kgb; o5.p[4] = vgts; o5.p[5] = qgc;
  // MEASUREMENT ROUND: gemm<0> launched 3x (idempotent — deterministic pure
  // function of hb/wt/hg). Total delta vs round-14 baseline (161.06us) =
  // 2 * T_gemm0. Completes the per-kernel budget (band=55us from round 13);
  // per-kernel profiler rows are masked by the harness's ~87us poison fills.
  // Duplicates removed next round.
  gemm_kernel<0><<<1926, 256, 0, stream>>>(hb, wt, hg, wt + (size_t)5 * 768 * 768, o5, nullptr);
  gemm_kernel<0><<<1926, 256, 0, stream>>>(hb, wt, hg, wt + (size_t)5 * 768 * 768, o5, nullptr);
  gemm_kernel<0><<<1926, 256, 0, stream>>>(hb, wt, hg, wt + (size_t)5 * 768 * 768, o5, nullptr);

  gcls_kernel<<<24, 256, 0, stream>>>(kb, vts, clss, kcls, vtcls);

  FusedArgs fa;
  fa.qB = qb; fa.kB = kb; fa.vT = vts; fa.kcls = kcls; fa.vtcls = vtcls;
  fa.qgc = qgc; fa.kgB = kgb; fa.vgT = vgts;
  fa.kv32 = kv32; fa.mv32 = mv32; fa.mc32 = mc32;
  fa.aout = aout; fa.pm = pm; fa.pl = pl; fa.pacc = pacc;
  band_kernel<<<864, 256, 0, stream>>>(fa);

  ogm_kernel<<<24, 256, 0, stream>>>(pm, pl, pacc, clss, aout);

  Outs6 dummy = {};
  gemm_kernel<1><<<384, 256, 0, stream>>>(aout, wt + (size_t)6 * 768 * 768, nullptr, nullptr, dummy, out);
}

// Round 16
// 159.604 us; speedup vs baseline: 1.7775x; 1.7775x over previous
//
#include <hip/hip_runtime.h>
#include <stdint.h>

typedef unsigned short u16;
typedef unsigned char u8;
typedef unsigned int u32;
typedef __attribute__((ext_vector_type(8))) short short8x;
typedef __attribute__((ext_vector_type(4))) float f32x4;
typedef __attribute__((ext_vector_type(16))) float f32x16;

#define DEV static __device__ __forceinline__

DEV u16 f2bf(float f) {
  union { float f; unsigned u; } v; v.f = f;
  unsigned r = v.u + 0x7FFFu + ((v.u >> 16) & 1u);
  return (u16)(r >> 16);
}
DEV int imin(int a, int b) { return a < b ? a : b; }
DEV int imax(int a, int b) { return a > b ? a : b; }
DEV float ex2(float x) { return __builtin_exp2f(x); }

DEV void gload16(const void* g, void* l) {
  __builtin_amdgcn_global_load_lds((const __attribute__((address_space(1))) void*)g,
                                   (__attribute__((address_space(3))) void*)l, 16, 0, 0);
}

DEV u32 cvtpk_bf16(float lo, float hi) {
  u32 r;
  asm("v_cvt_pk_bf16_f32 %0, %1, %2" : "=v"(r) : "v"(lo), "v"(hi));
  return r;
}
DEV void plswap(u32& a, u32& b) {
  asm("v_permlane32_swap_b32 %0, %1" : "+v"(a), "+v"(b));
}

#define LOG2E 1.44269504f

// ---------------------------------------------------------------------------
// Fused prep: blocks 0..1007 wconv (7 mats x 144 tiles); 1008..2031 embed
// (grid-stride); 2032 bits; 2033..2128 hgather-direct (h[clss] from emb/pos).
struct WPtrs { const float* p[7]; };

__global__ __launch_bounds__(256) void prep_kernel(
    WPtrs wp, const int* __restrict__ x, const float* __restrict__ emb,
    const float* __restrict__ pos, const int* __restrict__ clss,
    const int* __restrict__ mask, u16* __restrict__ wt, u16* __restrict__ hb,
    u16* __restrict__ hg, u32* __restrict__ kv32, u32* __restrict__ mv32,
    u32* __restrict__ mc32) {
  __shared__ __align__(16) char smraw[64 * 72 * 4];
  const int bid = blockIdx.x;
  const int t = threadIdx.x;

  if (bid < 1008) {
    // ---- weight convert+transpose: w[k][n] fp32 -> wt[mat][n][k] bf16 ----
    const int mat = bid / 144;
    const int inner = bid - mat * 144;
    const int kt = inner % 12, nt = inner / 12;
    const float* __restrict__ w = wp.p[mat];
    float(*tile)[72] = (float(*)[72])smraw;
    {
      const int kk = t >> 2, n0 = (t & 3) * 16;
      const float* src = w + (size_t)(kt * 64 + kk) * 768 + nt * 64 + n0;
#pragma unroll
      for (int i = 0; i < 4; ++i)
        *(float4*)&tile[kk][n0 + i * 4] = *(const float4*)(src + i * 4);
    }
    __syncthreads();
    {
      const int nn = t >> 2, k0 = (t & 3) * 16;
      u16* dst = wt + (size_t)(mat * 768 + nt * 64 + nn) * 768 + kt * 64 + k0;
      short8x v0, v1;
#pragma unroll
      for (int j = 0; j < 8; ++j) {
        v0[j] = (short)f2bf(tile[k0 + j][nn]);
        v1[j] = (short)f2bf(tile[k0 + 8 + j][nn]);
      }
      *(short8x*)dst = v0;
      *(short8x*)(dst + 8) = v1;
    }
    return;
  }
  if (bid < 2032) {
    // ---- h = emb[x] + pos -> bf16 (8192 x 768) ----
    const int vb = bid - 1008;
    const int n4 = 2 * 4096 * 192;
    for (int i = vb * 256 + t; i < n4; i += 1024 * 256) {
      const int r = i / 192;
      const int d4 = i - r * 192;
      const int s = r & 4095;
      const int tok = x[r];
      const float4 e = *(const float4*)(emb + (size_t)tok * 768 + d4 * 4);
      const float4 p = *(const float4*)(pos + (size_t)s * 768 + d4 * 4);
      union { u16 u[4]; uint2 v; } o;
      o.u[0] = f2bf(e.x + p.x);
      o.u[1] = f2bf(e.y + p.y);
      o.u[2] = f2bf(e.z + p.z);
      o.u[3] = f2bf(e.w + p.w);
      *(uint2*)(hb + (size_t)r * 768 + d4 * 4) = o.v;
    }
    return;
  }
  if (bid == 2032) {
    // ---- validity bitmasks ----
    u8* isg = (u8*)smraw;
    for (int i = t; i < 4096; i += 256) isg[i] = 0;
    __syncthreads();
    if (t < 64) isg[clss[t]] = 1;
    __syncthreads();
    {
      const int b = t >> 7, i = t & 127;
      u32 kv = 0, mvv = 0;
      for (int j = 0; j < 32; ++j) {
        const int key = i * 32 + j;
        const u32 m = (u32)(mask[b * 4096 + key] != 0);
        mvv |= m << j;
        kv |= (m & (u32)(isg[key] == 0)) << j;
      }
      kv32[b * 128 + i] = kv;
      mv32[b * 128 + i] = mvv;
    }
    if (t < 4) {
      const int b = t >> 1, wi = t & 1;
      u32 mc = 0;
      for (int j = 0; j < 32; ++j) {
        const int g = wi * 32 + j;
        mc |= (u32)(mask[b * 4096 + clss[g]] != 0) << j;
      }
      mc32[b * 2 + wi] = mc;
    }
    return;
  }
  // ---- hg[128][768]: h at clss rows, computed directly (identical f2bf) ----
  {
    const int i = (bid - 2033) * 256 + t;   // 0..24575 = 128 x 192
    const int r = i / 192, d4 = i - r * 192;
    const int b = r >> 6, g = r & 63;
    const int s = clss[g];
    const int tok = x[b * 4096 + s];
    const float4 e = *(const float4*)(emb + (size_t)tok * 768 + d4 * 4);
    const float4 p = *(const float4*)(pos + (size_t)s * 768 + d4 * 4);
    union { u16 u[4]; uint2 v; } o;
    o.u[0] = f2bf(e.x + p.x);
    o.u[1] = f2bf(e.y + p.y);
    o.u[2] = f2bf(e.z + p.z);
    o.u[3] = f2bf(e.w + p.w);
    *(uint2*)(hg + (size_t)r * 768 + d4 * 4) = o.v;
  }
}

// ---------------------------------------------------------------------------
// 128x128 bf16 MFMA GEMM, B pre-transposed (N x K), BK=64 double-buffered
// global_load_lds pipeline with counted vmcnt, raw s_barrier, and a FULL
// 3-bit (row&7)<<4 byte-XOR LDS swizzle at 16B granularity (conflict-free
// ds_read_b128 at quarter-wave granularity; residual 2-way is free).
// Swizzle is both-sides: stage source slot = (l&7)^(l>>3), read XOR (l15&7)<<4.
// K = 768 = 12 tiles of 64. XCD-local bx-major mapping (8-by groups).
struct Outs6 { u16* p[6]; };

template <int MODE>
__global__ __launch_bounds__(256) void gemm_kernel(const u16* __restrict__ A, const u16* __restrict__ Bt,
                                                   const u16* __restrict__ A2, const u16* __restrict__ Bt2,
                                                   Outs6 outs, float* __restrict__ outF) {
  __shared__ __align__(16) u16 smA[2][128 * 64];   // 32 KB
  __shared__ __align__(16) u16 smB[2][128 * 64];   // 32 KB
  const int t = threadIdx.x;
  const int l = t & 63, w = t >> 6;
  const int l15 = l & 15, grp = l >> 4;
  const int wm = w >> 1, wn = w & 1;
  int bx, by;
  bool qg = false;
  if (MODE == 0) {
    int id = blockIdx.x;
    if (id >= 1920) {                    // folded qg-compact part
      qg = true;
      bx = id - 1920;
      by = 0;
    } else {                             // 1920 = 8 XCDs x 240; bx-major, 8-by groups
      const int xcd = id & 7;
      const int j = id >> 3;             // 0..239
      by = xcd * 8 + (j & 7);
      bx = j >> 3;                       // 0..29
    }
  } else {                               // 384 = 8 XCDs x 48; bx-major, 8-by groups
    const int xcd = blockIdx.x & 7;
    const int j = blockIdx.x >> 3;       // 0..47
    by = xcd * 8 + (j & 7);
    bx = j >> 3;                         // 0..5
  }
  const u16* __restrict__ Ap = (MODE == 0 && qg) ? A2 : A;
  const u16* __restrict__ Btp = (MODE == 0 && qg) ? Bt2 : Bt;
  const int m0 = by * 128, n0 = bx * 128;
  const f32x4 zero4 = {0.f, 0.f, 0.f, 0.f};
  f32x4 acc[4][4];
#pragma unroll
  for (int mi = 0; mi < 4; ++mi)
#pragma unroll
    for (int ni = 0; ni < 4; ++ni) acc[mi][ni] = zero4;

  // stage source byte col within 128B row: slot (l&7) XOR row-bits (l>>3), *16B.
  const int sr = l >> 3;                      // row within 8-row group
  const int ssl = ((l & 7) ^ sr) << 4;        // swizzled source slot byte offset

  auto STAGE = [&](int kb, int d) {
#pragma unroll
    for (int c = 0; c < 4; ++c) {
      const int rg = w * 4 + c;        // 0..15
      const int r = rg * 8 + sr;       // 0..127
      gload16(Ap + (size_t)(m0 + r) * 768 + kb * 64 + (ssl >> 1), (char*)smA[d] + rg * 1024);
      gload16(Btp + (size_t)(n0 + r) * 768 + kb * 64 + (ssl >> 1), (char*)smB[d] + rg * 1024);
    }
  };
  const int xorf = (l15 & 7) << 4;            // read-side XOR: (row&7)<<4, row&7 = l15&7
  auto RDA = [&](int d, int mi, int kk) {
    return *(const short8x*)((const char*)smA[d] + (wm * 64 + mi * 16 + l15) * 128 + ((kk * 64 + grp * 16) ^ xorf));
  };
  auto RDB = [&](int d, int ni, int kk) {
    return *(const short8x*)((const char*)smB[d] + (wn * 64 + ni * 16 + l15) * 128 + ((kk * 64 + grp * 16) ^ xorf));
  };

  // prologue: stage tiles 0,1; validate tile 0 (8 of 16 loads retired)
  STAGE(0, 0);
  STAGE(1, 1);
  asm volatile("s_waitcnt vmcnt(8)" ::: "memory");
  __builtin_amdgcn_s_barrier();
  __builtin_amdgcn_sched_barrier(0);

  short8x a0[4], b0[4], a1[4], b1[4];
#pragma unroll
  for (int i = 0; i < 4; ++i) { a0[i] = RDA(0, i, 0); b0[i] = RDB(0, i, 0); }

  for (int kt = 0; kt < 12; ++kt) {
    const int cur = kt & 1;
#pragma unroll
    for (int i = 0; i < 4; ++i) { a1[i] = RDA(cur, i, 1); b1[i] = RDB(cur, i, 1); }
    __builtin_amdgcn_s_setprio(1);
#pragma unroll
    for (int mi = 0; mi < 4; ++mi)
#pragma unroll
      for (int ni = 0; ni < 4; ++ni)
        acc[mi][ni] = __builtin_amdgcn_mfma_f32_16x16x32_bf16(a0[mi], b0[ni], acc[mi][ni], 0, 0, 0);
    __builtin_amdgcn_s_setprio(0);
    if (kt < 11) {
      asm volatile("s_waitcnt lgkmcnt(0)" ::: "memory");
      __builtin_amdgcn_s_barrier();
      __builtin_amdgcn_sched_barrier(0);
      if (kt < 10) {
        STAGE(kt + 2, cur);
        asm volatile("s_waitcnt vmcnt(8)" ::: "memory");
      } else {
        asm volatile("s_waitcnt vmcnt(0)" ::: "memory");
      }
      __builtin_amdgcn_s_barrier();
      __builtin_amdgcn_sched_barrier(0);
#pragma unroll
      for (int i = 0; i < 4; ++i) { a0[i] = RDA(cur ^ 1, i, 0); b0[i] = RDB(cur ^ 1, i, 0); }
    }
    __builtin_amdgcn_s_setprio(1);
#pragma unroll
    for (int mi = 0; mi < 4; ++mi)
#pragma unroll
      for (int ni = 0; ni < 4; ++ni)
        acc[mi][ni] = __builtin_amdgcn_mfma_f32_16x16x32_bf16(a1[mi], b1[ni], acc[mi][ni], 0, 0, 0);
    __builtin_amdgcn_s_setprio(0);
  }

  if (MODE == 0) {
    if (qg) {
      u16* __restrict__ base = outs.p[5];
#pragma unroll
      for (int mi = 0; mi < 4; ++mi)
#pragma unroll
        for (int ni = 0; ni < 4; ++ni) {
          const int col = n0 + wn * 64 + ni * 16 + l15;
          const int hd = col >> 6, dh = col & 63;
#pragma unroll
          for (int rr = 0; rr < 4; ++rr) {
            const int row = wm * 64 + mi * 16 + grp * 4 + rr;   // 0..127
            const int b = row >> 6, g = row & 63;
            base[((size_t)(b * 12 + hd) * 64 + g) * 64 + dh] = f2bf(acc[mi][ni][rr] * 0.125f * LOG2E);
          }
        }
      return;
    }
    const int mat = bx / 6;               // 5 mats: q,k,v,kg,vg
    const int inn0 = n0 - mat * 768 + wn * 64;
    u16* __restrict__ base = outs.p[mat];
    if (mat == 2 || mat == 4) {
#pragma unroll
      for (int mi = 0; mi < 4; ++mi) {
        const int row0 = m0 + wm * 64 + mi * 16 + grp * 4;
        const int b = row0 >> 12, s = row0 & 4095;
#pragma unroll
        for (int ni = 0; ni < 4; ++ni) {
          const int col = inn0 + ni * 16 + l15;
          const int hd = col >> 6, dh = col & 63;
          union { u16 u[4]; uint2 v; } o;
#pragma unroll
          for (int rr = 0; rr < 4; ++rr) o.u[rr] = f2bf(acc[mi][ni][rr]);
          *(uint2*)(base + ((size_t)(b * 12 + hd) * 64 + dh) * 4096 + s) = o.v;
        }
      }
    } else {
      const float scl = (mat == 0) ? 0.125f * LOG2E : 1.0f;
#pragma unroll
      for (int mi = 0; mi < 4; ++mi)
#pragma unroll
        for (int ni = 0; ni < 4; ++ni) {
          const int col = inn0 + ni * 16 + l15;
          const int hd = col >> 6, dh = col & 63;
#pragma unroll
          for (int rr = 0; rr < 4; ++rr) {
            const int row = m0 + wm * 64 + mi * 16 + grp * 4 + rr;
            const int b = row >> 12, s = row & 4095;
            base[((size_t)(b * 12 + hd) * 4096 + s) * 64 + dh] = f2bf(acc[mi][ni][rr] * scl);
          }
        }
    }
  } else {
#pragma unroll
    for (int mi = 0; mi < 4; ++mi)
#pragma unroll
      for (int rr = 0; rr < 4; ++rr) {
        const int row = m0 + wm * 64 + mi * 16 + grp * 4 + rr;
#pragma unroll
        for (int ni = 0; ni < 4; ++ni) {
          const int col = n0 + wn * 64 + ni * 16 + l15;
          outF[(size_t)row * 768 + col] = acc[mi][ni][rr];
        }
      }
  }
}

// ---------------------------------------------------------------------------
// Gather K rows at clss -> kcls; vtcls gathered from vT (v is only stored transposed).
__global__ __launch_bounds__(256) void gcls_kernel(const u16* __restrict__ kB, const u16* __restrict__ vTs,
                                                   const int* __restrict__ clss,
                                                   u16* __restrict__ kcls, u16* __restrict__ vtcls) {
  const int bh = blockIdx.x;
  __shared__ int sc[64];
  const int t = threadIdx.x;
  if (t < 64) sc[t] = clss[t];
  __syncthreads();
  {
    const int g = t >> 2, d0 = (t & 3) * 16;
    const int row = sc[g];
    const u16* pk = kB + ((size_t)bh * 4096 + row) * 64 + d0;
    u16* ok = kcls + ((size_t)bh * 64 + g) * 64 + d0;
    *(short8x*)ok = *(const short8x*)pk;
    *(short8x*)(ok + 8) = *(const short8x*)(pk + 8);
  }
  {
    const int dh = t >> 2, g0 = (t & 3) * 16;
    const u16* vrow = vTs + ((size_t)bh * 64 + dh) * 4096;
    short8x v0, v1;
#pragma unroll
    for (int j = 0; j < 8; ++j) {
      v0[j] = (short)vrow[sc[g0 + j]];
      v1[j] = (short)vrow[sc[g0 + 8 + j]];
    }
    u16* o = vtcls + ((size_t)bh * 64 + dh) * 64 + g0;
    *(short8x*)o = v0;
    *(short8x*)(o + 8) = v1;
  }
}

// ---------------------------------------------------------------------------
// Swapped-operand 32x32 attention core. Softmax fully in-register.
struct AttnState {
  f32x16 a0, a1;   // out^T accumulators for dh-tiles 0,1
  float m, l;
};

// Shared softmax+PV tail given scores s0,s1 and V-fragment loader lambda.
#define ATTN_SOFTMAX_PV(S, s0, s1, vm0, vm1, LOADV0, LOADV1)                        \
  {                                                                                  \
    float mx[8];                                                                     \
    _Pragma("unroll") for (int e = 0; e < 8; ++e)                                    \
        mx[e] = fmaxf(fmaxf(s0[e], s0[e + 8]), fmaxf(s1[e], s1[e + 8]));             \
    mx[0] = fmaxf(mx[0], mx[4]); mx[1] = fmaxf(mx[1], mx[5]);                        \
    mx[2] = fmaxf(mx[2], mx[6]); mx[3] = fmaxf(mx[3], mx[7]);                        \
    mx[0] = fmaxf(mx[0], mx[2]); mx[1] = fmaxf(mx[1], mx[3]);                        \
    float mv = fmaxf(mx[0], mx[1]);                                                  \
    mv = fmaxf(mv, __shfl_xor(mv, 32));                                              \
    if (!__all(mv <= S.m + 8.f)) {                                                   \
      const float mn = fmaxf(S.m, mv);                                               \
      const float sc = ex2(S.m - mn);                                                \
      S.m = mn; S.l *= sc;                                                           \
      _Pragma("unroll") for (int e = 0; e < 16; ++e) { S.a0[e] *= sc; S.a1[e] *= sc; } \
    }                                                                                \
    float p0[16], p1[16];                                                            \
    if ((vm0 & vm1) == 0xFFFFFFFFu) {                                                \
      _Pragma("unroll") for (int e = 0; e < 16; ++e) {                               \
        p0[e] = ex2(s0[e] - S.m); p1[e] = ex2(s1[e] - S.m);                          \
      }                                                                              \
    } else {                                                                         \
      const u32 w0 = vm0 >> (hf * 4), w1 = vm1 >> (hf * 4);                          \
      _Pragma("unroll") for (int e = 0; e < 16; ++e) {                               \
        const int cr = (e & 3) + 8 * (e >> 2);                                       \
        p0[e] = ex2(s0[e] - S.m) * (float)((w0 >> cr) & 1u);                         \
        p1[e] = ex2(s1[e] - S.m) * (float)((w1 >> cr) & 1u);                         \
      }                                                                              \
    }                                                                                \
    float sm[8];                                                                     \
    _Pragma("unroll") for (int e = 0; e < 8; ++e)                                    \
        sm[e] = (p0[e] + p0[e + 8]) + (p1[e] + p1[e + 8]);                           \
    sm[0] += sm[4]; sm[1] += sm[5]; sm[2] += sm[6]; sm[3] += sm[7];                  \
    sm[0] += sm[2]; sm[1] += sm[3];                                                  \
    float ls = sm[0] + sm[1];                                                        \
    ls += __shfl_xor(ls, 32);                                                        \
    S.l += ls;                                                                       \
    _Pragma("unroll") for (int st = 0; st < 2; ++st) {                               \
      const float* pp = st ? p1 : p0;                                                \
      _Pragma("unroll") for (int c = 0; c < 2; ++c) {                                \
        u32 A1 = cvtpk_bf16(pp[8 * c + 0], pp[8 * c + 1]);                           \
        u32 A2 = cvtpk_bf16(pp[8 * c + 2], pp[8 * c + 3]);                           \
        u32 B1 = cvtpk_bf16(pp[8 * c + 4], pp[8 * c + 5]);                           \
        u32 B2 = cvtpk_bf16(pp[8 * c + 6], pp[8 * c + 7]);                           \
        plswap(A1, B1); plswap(A2, B2);                                              \
        union { u32 w[4]; short8x v; } u;                                            \
        u.w[0] = A1; u.w[1] = A2; u.w[2] = B1; u.w[3] = B2;                          \
        const int sc4 = st * 2 + c;                                                  \
        const short8x vf0 = LOADV0(sc4);                                             \
        const short8x vf1 = LOADV1(sc4);                                             \
        S.a0 = __builtin_amdgcn_mfma_f32_32x32x16_bf16(vf0, u.v, S.a0, 0, 0, 0);     \
        S.a1 = __builtin_amdgcn_mfma_f32_32x32x16_bf16(vf1, u.v, S.a1, 0, 0, 0);     \
      }                                                                              \
    }                                                                                \
  }

// Global-memory tile (og path).
DEV void attn_tile64(const u16* __restrict__ kp, const u16* __restrict__ vp, int vstr,
                     u32 vm0, u32 vm1, const short8x* qf, AttnState& S, int l31, int hf) {
  const int h8 = hf * 8;
  const f32x16 z16 = {0.f};
  f32x16 s0 = z16, s1 = z16;
  const u16* kr0 = kp + (size_t)l31 * 64 + h8;
  const u16* kr1 = kr0 + 32 * 64;
#pragma unroll
  for (int ks = 0; ks < 4; ++ks) {
    const short8x kf0 = *(const short8x*)(kr0 + ks * 16);
    const short8x kf1 = *(const short8x*)(kr1 + ks * 16);
    s0 = __builtin_amdgcn_mfma_f32_32x32x16_bf16(kf0, qf[ks], s0, 0, 0, 0);
    s1 = __builtin_amdgcn_mfma_f32_32x32x16_bf16(kf1, qf[ks], s1, 0, 0, 0);
  }
#define LV0(sc4) (*(const short8x*)(vp + (sc4) * 16 + h8 + (size_t)l31 * vstr))
#define LV1(sc4) (*(const short8x*)(vp + (sc4) * 16 + h8 + (size_t)(32 + l31) * vstr))
  ATTN_SOFTMAX_PV(S, s0, s1, vm0, vm1, LV0, LV1)
#undef LV0
#undef LV1
}

// LDS tile (band path): Kl/Vl are [64 rows][128B] with byte-XOR swizzle
// ((row&7)<<4) applied to both the staged source and the reads (rule 21).
DEV void attn_tile64_lds(const char* __restrict__ Kl, const char* __restrict__ Vl,
                         u32 vm0, u32 vm1, const short8x* qf, AttnState& S, int l31, int hf) {
  const int swz = (l31 & 7) << 4;
  const f32x16 z16 = {0.f};
  f32x16 s0 = z16, s1 = z16;
#pragma unroll
  for (int ks = 0; ks < 4; ++ks) {
    const int cb = (hf * 16 + ks * 32) ^ swz;
    const short8x kf0 = *(const short8x*)(Kl + l31 * 128 + cb);
    const short8x kf1 = *(const short8x*)(Kl + (32 + l31) * 128 + cb);
    s0 = __builtin_amdgcn_mfma_f32_32x32x16_bf16(kf0, qf[ks], s0, 0, 0, 0);
    s1 = __builtin_amdgcn_mfma_f32_32x32x16_bf16(kf1, qf[ks], s1, 0, 0, 0);
  }
#define LV0(sc4) (*(const short8x*)(Vl + l31 * 128 + (((sc4) * 32 + hf * 16) ^ swz)))
#define LV1(sc4) (*(const short8x*)(Vl + (32 + l31) * 128 + (((sc4) * 32 + hf * 16) ^ swz)))
  ATTN_SOFTMAX_PV(S, s0, s1, vm0, vm1, LV0, LV1)
#undef LV0
#undef LV1
}

DEV u32 bandmask32(int q, int kb2) {
  const int lo = imax(q - 256 - kb2, 0);
  const int hi = imin(q + 256 - kb2, 31);
  if (hi < lo) return 0u;
  return (0xFFFFFFFFu << lo) & (0xFFFFFFFFu >> (31 - hi));
}

// ---------------------------------------------------------------------------
// Fused attention:
//  blocks 0..95   : global-token partials (wave = (bh,qsub,slice of 8)), global reads
//  blocks 96..863 : band; block = 128 queries (4 waves x 32q); K/V^T staged in
//                   LDS with 2-deep counted-vmcnt pipeline.
// NOTE: min-waves stays at 3 (round-6 spill lesson).
struct FusedArgs {
  const u16 *qB, *kB, *vT, *kcls, *vtcls, *qgc, *kgB, *vgT;
  const u32 *kv32, *mv32, *mc32;
  u16* aout;
  float *pm, *pl, *pacc;
};

__global__ __launch_bounds__(256, 3) void band_kernel(FusedArgs a) {
  const int t = threadIdx.x;
  const int w = t >> 6, l = t & 63;
  const int l31 = l & 31, hf = l >> 5, h4 = hf * 4;
  const f32x16 z16 = {0.f};

  __shared__ __align__(16) char Ktile[2][8192];   // 64 keys x 128B (swizzled rows)
  __shared__ __align__(16) char Vtile[2][8192];   // 64 dh x 128B (swizzled rows)

  if (blockIdx.x < 96) {
    // ---- global-token attention partial (global reads) ----
    const int wid = blockIdx.x * 4 + w;     // 384 waves
    const int sl = wid & 7;
    const int qsub = (wid >> 3) & 1;
    const int bh = wid >> 4;
    const int b = bh / 12;
    const int q = qsub * 32 + l31;

    const u16* kgb = a.kgB + (size_t)bh * 4096 * 64;
    const u16* vgb = a.vgT + (size_t)bh * 64 * 4096;
    short8x qf[4];
#pragma unroll
    for (int ks = 0; ks < 4; ++ks)
      qf[ks] = *(const short8x*)(a.qgc + ((size_t)bh * 64 + q) * 64 + ks * 16 + hf * 8);

    AttnState S;
    S.a0 = z16; S.a1 = z16; S.m = -60.f; S.l = 0.f;
    for (int tt = sl * 8; tt < sl * 8 + 8; ++tt) {
      const int kb = tt * 64;
      const u32 vm0 = a.mv32[b * 128 + tt * 2];
      const u32 vm1 = a.mv32[b * 128 + tt * 2 + 1];
      attn_tile64(kgb + (size_t)kb * 64, vgb + kb, 4096, vm0, vm1, qf, S, l31, hf);
    }
    const int pbase = (bh * 8 + sl) * 64;
    float* pr = a.pacc + ((size_t)pbase + q) * 64;
#pragma unroll
    for (int rq = 0; rq < 4; ++rq) {
      f32x4 v0 = {S.a0[rq * 4 + 0], S.a0[rq * 4 + 1], S.a0[rq * 4 + 2], S.a0[rq * 4 + 3]};
      f32x4 v1 = {S.a1[rq * 4 + 0], S.a1[rq * 4 + 1], S.a1[rq * 4 + 2], S.a1[rq * 4 + 3]};
      *(f32x4*)(pr + rq * 8 + h4) = v0;
      *(f32x4*)(pr + 32 + rq * 8 + h4) = v1;
    }
    if (hf == 0) {
      a.pm[pbase + q] = S.m;
      a.pl[pbase + q] = S.l;
    }
    return;
  }

  // ---- band path: 768 blocks of 128 queries; 4 waves x 32q, shared LDS tiles ----
  int bid = blockIdx.x - 96;
  bid = (bid & 7) * 96 + (bid >> 3);   // XCD chunking (768 = 8 * 96, bijective)
  const int qblk = bid & 31;
  const int h = (bid >> 5) % 12;
  const int b = bid / 384;
  const int bh = b * 12 + h;
  const int q0b = qblk * 128;
  const int q0w = q0b + w * 32;
  const int q = q0w + l31;

  const u16* kbh = a.kB + (size_t)bh * 4096 * 64;
  const u16* vbh = a.vT + (size_t)bh * 64 * 4096;
  const u16* kcb = a.kcls + (size_t)bh * 4096;
  const u16* vcb = a.vtcls + (size_t)bh * 4096;

  short8x qf[4];
#pragma unroll
  for (int ks = 0; ks < 4; ++ks)
    qf[ks] = *(const short8x*)(a.qB + ((size_t)bh * 4096 + q) * 64 + ks * 16 + hf * 8);

  AttnState S;
  S.a0 = z16; S.a1 = z16; S.m = -60.f; S.l = 0.f;

  const int tloB = imax(0, q0b - 256) >> 6;
  const int thiB = imin(63, (q0b + 383) >> 6);
  const int nB = thiB - tloB + 1;                   // block band tiles (6..11); tile nB = clss
  const int tlo_w = (imax(0, q0w - 256) >> 6) - tloB;
  const int thi_w = (imin(63, (q0w + 287) >> 6)) - tloB;

  // stage tile j (j<nB band, j==nB clss) into LDS buf; 4 gload16 per wave.
  auto STAGEi = [&](int j, int buf) {
    const u16* ksrc;
    const u16* vsrc;
    int vstr;
    if (j == nB) { ksrc = kcb; vsrc = vcb; vstr = 64; }
    else {
      ksrc = kbh + (size_t)(tloB + j) * 64 * 64;
      vsrc = vbh + (size_t)(tloB + j) * 64;
      vstr = 4096;
    }
#pragma unroll
    for (int c = 0; c < 2; ++c) {
      const int rw = w + 4 * c;                     // row-group 0..7
      const int row = rw * 8 + (l >> 3);
      const int seg = (l & 7) ^ (row & 7);
      gload16(ksrc + (size_t)row * 64 + seg * 8, Ktile[buf] + rw * 1024);
      gload16(vsrc + (size_t)row * vstr + seg * 8, Vtile[buf] + rw * 1024);
    }
  };

  // prologue: 2-deep prefetch; wait tile 0 only (vmcnt(4): tile 1's 4 loads stay in flight)
  STAGEi(0, 0);
  STAGEi(1, 1);
  asm volatile("s_waitcnt vmcnt(4)" ::: "memory");
  __builtin_amdgcn_s_barrier();
  __builtin_amdgcn_sched_barrier(0);

  for (int i = 0; i <= nB; ++i) {
    const int buf = i & 1;
    const bool isG = (i == nB);
    if (isG || (i >= tlo_w && i <= thi_w)) {
      u32 vm0, vm1;
      if (isG) {
        vm0 = a.mc32[b * 2];
        vm1 = a.mc32[b * 2 + 1];
      } else {
        const int tt = tloB + i;
        const int kb = tt * 64;
        vm0 = a.kv32[b * 128 + tt * 2];
        vm1 = a.kv32[b * 128 + tt * 2 + 1];
        const int d0 = kb - q0w, d1 = kb + 32 - q0w;
        if (d0 < -225 || d0 > 225) vm0 &= bandmask32(q, kb);
        if (d1 < -225 || d1 > 225) vm1 &= bandmask32(q, kb + 32);
      }
      attn_tile64_lds(Ktile[buf], Vtile[buf], vm0, vm1, qf, S, l31, hf);
    }
    if (i < nB) {
      // WAR: all waves done reading buf before restaging it
      asm volatile("s_waitcnt lgkmcnt(0)" ::: "memory");
      __builtin_amdgcn_s_barrier();
      __builtin_amdgcn_sched_barrier(0);
      if (i + 2 <= nB) {
        STAGEi(i + 2, buf);
        asm volatile("s_waitcnt vmcnt(4)" ::: "memory");   // tile i+1 landed; i+2 in flight
      } else {
        asm volatile("s_waitcnt vmcnt(0)" ::: "memory");   // final tile landed
      }
      __builtin_amdgcn_s_barrier();
      __builtin_amdgcn_sched_barrier(0);
    }
  }

  // finalize: out = acc/l, store (B,S,D) bf16 (lane q owns row q)
  const float inv = 1.f / S.l;
  u16* ob = a.aout + ((size_t)b * 4096 + q) * 768 + h * 64;
#pragma unroll
  for (int rq = 0; rq < 4; ++rq) {
    union { u16 s[4]; uint2 v; } o0, o1;
#pragma unroll
    for (int j = 0; j < 4; ++j) {
      o0.s[j] = f2bf(S.a0[rq * 4 + j] * inv);
      o1.s[j] = f2bf(S.a1[rq * 4 + j] * inv);
    }
    *(uint2*)(ob + rq * 8 + h4) = o0.v;
    *(uint2*)(ob + 32 + rq * 8 + h4) = o1.v;
  }
}

// ---------------------------------------------------------------------------
// Global-token attention merge: combine 8 key-slice partials into clss rows of aout.
__global__ __launch_bounds__(256) void ogm_kernel(const float* __restrict__ pm, const float* __restrict__ pl,
                                                  const float* __restrict__ pacc, const int* __restrict__ clss,
                                                  u16* __restrict__ aout) {
  const int bh = blockIdx.x;
  const int b = bh / 12, h = bh % 12;
  const int t = threadIdx.x;
  const int r = t >> 2, cs = (t & 3) * 16;
  float mv[8];
  float M = -1e30f;
#pragma unroll
  for (int s = 0; s < 8; ++s) {
    mv[s] = pm[(bh * 8 + s) * 64 + r];
    M = fmaxf(M, mv[s]);
  }
  float L = 0.f, f[8];
#pragma unroll
  for (int s = 0; s < 8; ++s) {
    f[s] = ex2(mv[s] - M);
    L += pl[(bh * 8 + s) * 64 + r] * f[s];
  }
  float o[16];
#pragma unroll
  for (int j = 0; j < 16; ++j) o[j] = 0.f;
#pragma unroll
  for (int s = 0; s < 8; ++s) {
    const float* pr = pacc + (size_t)(bh * 8 + s) * 4096 + r * 64 + cs;
#pragma unroll
    for (int j4 = 0; j4 < 4; ++j4) {
      const float4 a = *(const float4*)(pr + j4 * 4);
      o[j4 * 4 + 0] += a.x * f[s];
      o[j4 * 4 + 1] += a.y * f[s];
      o[j4 * 4 + 2] += a.z * f[s];
      o[j4 * 4 + 3] += a.w * f[s];
    }
  }
  const float inv = 1.f / L;
  short8x v0, v1;
#pragma unroll
  for (int j = 0; j < 8; ++j) {
    v0[j] = (short)f2bf(o[j] * inv);
    v1[j] = (short)f2bf(o[8 + j] * inv);
  }
  u16* op = aout + ((size_t)b * 4096 + clss[r]) * 768 + h * 64 + cs;
  *(short8x*)op = v0;
  *(short8x*)(op + 8) = v1;
}

// ---------------------------------------------------------------------------
extern "C" void kernel_launch(void* const* d_in, const int* in_sizes, int n_in,
                              void* d_out, int out_size, void* d_ws, size_t ws_size,
                              hipStream_t stream) {
  (void)in_sizes; (void)n_in; (void)out_size; (void)ws_size;
  const int* x = (const int*)d_in[0];
  const int* mask = (const int*)d_in[1];
  const int* clss = (const int*)d_in[2];
  const float* emb = (const float*)d_in[3];
  const float* pos = (const float*)d_in[4];
  const float* wq = (const float*)d_in[5];
  const float* wk = (const float*)d_in[6];
  const float* wv = (const float*)d_in[7];
  const float* wo = (const float*)d_in[8];
  const float* wqg = (const float*)d_in[9];
  const float* wkg = (const float*)d_in[10];
  const float* wvg = (const float*)d_in[11];
  float* out = (float*)d_out;

  char* ws = (char*)d_ws;
  size_t off = 0;
  auto alloc = [&](size_t n) { char* p = ws + off; off = (off + n + 255) & ~(size_t)255; return p; };
  const size_t SZ = (size_t)2 * 12 * 4096 * 64 * 2;  // one (B,H,S,DH) bf16 buffer
  u16* hb = (u16*)alloc(SZ);
  u16* wt = (u16*)alloc((size_t)7 * 768 * 768 * 2);
  u16* qb = (u16*)alloc(SZ);
  u16* kb = (u16*)alloc(SZ);
  u16* kgb = (u16*)alloc(SZ);
  u16* vts = (u16*)alloc(SZ);    // v, stored transposed (B,H,DH,S) by gemm<0>
  u16* vgts = (u16*)alloc(SZ);   // vg, stored transposed
  u16* hg = (u16*)alloc((size_t)128 * 768 * 2);
  u16* qgc = (u16*)alloc((size_t)24 * 64 * 64 * 2);
  u16* kcls = (u16*)alloc((size_t)24 * 64 * 64 * 2);
  u16* vtcls = (u16*)alloc((size_t)24 * 64 * 64 * 2);
  u32* kv32 = (u32*)alloc(256 * 4);
  u32* mv32 = (u32*)alloc(256 * 4);
  u32* mc32 = (u32*)alloc(4 * 4);
  u16* aout = (u16*)alloc(SZ);
  float* pm = (float*)alloc((size_t)192 * 64 * 4);
  float* pl = (float*)alloc((size_t)192 * 64 * 4);
  float* pacc = (float*)alloc((size_t)192 * 4096 * 4);

  WPtrs wp;
  wp.p[0] = wq; wp.p[1] = wk; wp.p[2] = wv; wp.p[3] = wkg; wp.p[4] = wvg; wp.p[5] = wqg; wp.p[6] = wo;

  prep_kernel<<<2129, 256, 0, stream>>>(wp, x, emb, pos, clss, mask, wt, hb, hg, kv32, mv32, mc32);

  Outs6 o5;
  o5.p[0] = qb; o5.p[1] = kb; o5.p[2] = vts; o5.p[3] = kgb; o5.p[4] = vgts; o5.p[5] = qgc;
  gemm_kernel<0><<<1926, 256, 0, stream>>>(hb, wt, hg, wt + (size_t)5 * 768 * 768, o5, nullptr);

  gcls_kernel<<<24, 256, 0, stream>>>(kb, vts, clss, kcls, vtcls);

  FusedArgs fa;
  fa.qB = qb; fa.kB = kb; fa.vT = vts; fa.kcls = kcls; fa.vtcls = vtcls;
  fa.qgc = qgc; fa.kgB = kgb; fa.vgT = vgts;
  fa.kv32 = kv32; fa.mv32 = mv32; fa.mc32 = mc32;
  fa.aout = aout; fa.pm = pm; fa.pl = pl; fa.pacc = pacc;
  band_kernel<<<864, 256, 0, stream>>>(fa);

  ogm_kernel<<<24, 256, 0, stream>>>(pm, pl, pacc, clss, aout);

  Outs6 dummy = {};
  gemm_kernel<1><<<384, 256, 0, stream>>>(aout, wt + (size_t)6 * 768 * 768, nullptr, nullptr, dummy, out);
}